// Round 1
// baseline (163.287 us; speedup 1.0000x reference)
//
#include <hip/hip_runtime.h>

// DepthwiseMultiScaleFIR: 4 causal depthwise convs (k=3,7,15,31), fused.
// x: [B=4, L=4096, C=2048] fp32 (channel innermost). w_k: [C, 1, k].
// y_k[b,t,c] = sum_j w_k[c,j] * x[b, t-(k-1)+j, c]   (cross-correlation, causal)

#define BB 4
#define LL 4096
#define CC 2048
#define TT 32     // timesteps per thread
#define HALO 30   // max kernel size - 1

__global__ __launch_bounds__(256) void fir_fused_kernel(
    const float* __restrict__ x,
    const float* __restrict__ w0, const float* __restrict__ w1,
    const float* __restrict__ w2, const float* __restrict__ w3,
    float* __restrict__ out)
{
    const int c  = blockIdx.x * 256 + threadIdx.x;   // channel (contiguous across lanes)
    const int t0 = blockIdx.y * TT;                  // tile start time
    const int b  = blockIdx.z;

    const long long base = (long long)b * LL * CC + c;

    // --- load x window: [t0-30, t0+31] for this channel; coalesced across lanes
    float xs[TT + HALO];
#pragma unroll
    for (int j = 0; j < TT + HALO; ++j) {
        const int t = t0 - HALO + j;
        xs[j] = (t >= 0) ? x[base + (long long)t * CC] : 0.0f;
    }

    // --- weights for this channel into registers (L2/L3-resident, tiny)
    float a0[3], a1[7], a2[15], a3[31];
#pragma unroll
    for (int j = 0; j < 3;  ++j) a0[j] = w0[c * 3  + j];
#pragma unroll
    for (int j = 0; j < 7;  ++j) a1[j] = w1[c * 7  + j];
#pragma unroll
    for (int j = 0; j < 15; ++j) a2[j] = w2[c * 15 + j];
#pragma unroll
    for (int j = 0; j < 31; ++j) a3[j] = w3[c * 31 + j];

    const long long N = (long long)BB * LL * CC;
    float* __restrict__ o0 = out;
    float* __restrict__ o1 = out + N;
    float* __restrict__ o2 = out + 2 * N;
    float* __restrict__ o3 = out + 3 * N;

    // y_k at abs time t0+t uses x[t0+t-(k-1)+j] = xs[t + (30-(k-1)) + j]
#pragma unroll
    for (int t = 0; t < TT; ++t) {
        float y0 = 0.f, y1 = 0.f, y2 = 0.f, y3 = 0.f;
#pragma unroll
        for (int j = 0; j < 31; ++j) y3 += a3[j] * xs[t + j];
#pragma unroll
        for (int j = 0; j < 15; ++j) y2 += a2[j] * xs[t + 16 + j];
#pragma unroll
        for (int j = 0; j < 7;  ++j) y1 += a1[j] * xs[t + 24 + j];
#pragma unroll
        for (int j = 0; j < 3;  ++j) y0 += a0[j] * xs[t + 28 + j];

        const long long oidx = base + (long long)(t0 + t) * CC;
        o0[oidx] = y0;
        o1[oidx] = y1;
        o2[oidx] = y2;
        o3[oidx] = y3;
    }
}

extern "C" void kernel_launch(void* const* d_in, const int* in_sizes, int n_in,
                              void* d_out, int out_size, void* d_ws, size_t ws_size,
                              hipStream_t stream)
{
    const float* x  = (const float*)d_in[0];
    const float* w0 = (const float*)d_in[1];
    const float* w1 = (const float*)d_in[2];
    const float* w2 = (const float*)d_in[3];
    const float* w3 = (const float*)d_in[4];
    float* out = (float*)d_out;

    dim3 grid(CC / 256, LL / TT, BB);
    dim3 block(256);
    hipLaunchKernelGGL(fir_fused_kernel, grid, block, 0, stream,
                       x, w0, w1, w2, w3, out);
}

// Round 2
// 123.247 us; speedup vs baseline: 1.3249x; 1.3249x over previous
//
#include <hip/hip_runtime.h>

// DepthwiseMultiScaleFIR: 4 causal depthwise convs (k=3,7,15,31), fused.
// x: [B=4, L=4096, C=2048] fp32 (channel innermost). w_k: [C, 1, k].
// y_k[b,t,c] = sum_j w_k[c,j] * x[b, t-(k-1)+j, c]
//
// Streaming structure: each block owns (b, 256-channel chunk, 128-timestep
// strip). A register-carried sliding window (HALO=30 + TT=16 floats/thread)
// means each x element is loaded from DRAM exactly once per strip (boundary
// halo only: 1.23x amplification vs 1.94x for independent 32-tiles).
// Outputs are streamed with nontemporal stores so the 537 MB write stream
// doesn't evict x from L2/L3.

#define BB 4
#define LL 4096
#define CC 2048
#define TT 16      // timesteps computed per inner iteration
#define HALO 30    // max kernel size - 1
#define STRIP 128  // timesteps per block

__global__ __launch_bounds__(256) void fir_fused_stream(
    const float* __restrict__ x,
    const float* __restrict__ w0, const float* __restrict__ w1,
    const float* __restrict__ w2, const float* __restrict__ w3,
    float* __restrict__ out)
{
    const int c  = blockIdx.x * 256 + threadIdx.x;   // channel (contiguous lanes)
    const int tb = blockIdx.y * STRIP;               // strip start time
    const int b  = blockIdx.z;

    const long long base = (long long)b * LL * CC + c;

    // --- weights for this channel into registers
    float a0[3], a1[7], a2[15], a3[31];
#pragma unroll
    for (int j = 0; j < 3;  ++j) a0[j] = w0[c * 3  + j];
#pragma unroll
    for (int j = 0; j < 7;  ++j) a1[j] = w1[c * 7  + j];
#pragma unroll
    for (int j = 0; j < 15; ++j) a2[j] = w2[c * 15 + j];
#pragma unroll
    for (int j = 0; j < 31; ++j) a3[j] = w3[c * 31 + j];

    // --- prologue: halo window [tb-30, tb)
    float xs[HALO + TT];
#pragma unroll
    for (int j = 0; j < HALO; ++j) {
        const int t = tb - HALO + j;
        xs[j] = (t >= 0) ? x[base + (long long)t * CC] : 0.0f;
    }

    const long long N = (long long)BB * LL * CC;
    float* __restrict__ o0 = out;
    float* __restrict__ o1 = out + N;
    float* __restrict__ o2 = out + 2 * N;
    float* __restrict__ o3 = out + 3 * N;

    for (int it = 0; it < STRIP / TT; ++it) {
        const int t0 = tb + it * TT;

        // load TT new timesteps (coalesced 256 B/wave each)
#pragma unroll
        for (int j = 0; j < TT; ++j)
            xs[HALO + j] = x[base + (long long)(t0 + j) * CC];

        // compute + stream out
#pragma unroll
        for (int t = 0; t < TT; ++t) {
            float y0 = 0.f, y1 = 0.f, y2 = 0.f, y3 = 0.f;
#pragma unroll
            for (int j = 0; j < 31; ++j) y3 += a3[j] * xs[t + j];
#pragma unroll
            for (int j = 0; j < 15; ++j) y2 += a2[j] * xs[t + 16 + j];
#pragma unroll
            for (int j = 0; j < 7;  ++j) y1 += a1[j] * xs[t + 24 + j];
#pragma unroll
            for (int j = 0; j < 3;  ++j) y0 += a0[j] * xs[t + 28 + j];

            const long long oidx = base + (long long)(t0 + t) * CC;
            __builtin_nontemporal_store(y0, o0 + oidx);
            __builtin_nontemporal_store(y1, o1 + oidx);
            __builtin_nontemporal_store(y2, o2 + oidx);
            __builtin_nontemporal_store(y3, o3 + oidx);
        }

        // slide window: carry last HALO values forward (register moves)
#pragma unroll
        for (int j = 0; j < HALO; ++j) xs[j] = xs[TT + j];
    }
}

extern "C" void kernel_launch(void* const* d_in, const int* in_sizes, int n_in,
                              void* d_out, int out_size, void* d_ws, size_t ws_size,
                              hipStream_t stream)
{
    const float* x  = (const float*)d_in[0];
    const float* w0 = (const float*)d_in[1];
    const float* w1 = (const float*)d_in[2];
    const float* w2 = (const float*)d_in[3];
    const float* w3 = (const float*)d_in[4];
    float* out = (float*)d_out;

    dim3 grid(CC / 256, LL / STRIP, BB);  // (8, 32, 4) = 1024 blocks
    dim3 block(256);
    hipLaunchKernelGGL(fir_fused_stream, grid, block, 0, stream,
                       x, w0, w1, w2, w3, out);
}

// Round 4
// 111.684 us; speedup vs baseline: 1.4620x; 1.1035x over previous
//
#include <hip/hip_runtime.h>

// DepthwiseMultiScaleFIR: 4 causal depthwise convs (k=3,7,15,31), fused.
// x: [B=4, L=4096, C=2048] fp32 (channel innermost). w_k: [C, 1, k].
// y_k[b,t,c] = sum_j w_k[c,j] * x[b, t-(k-1)+j, c]
//
// v4: 2 channels per thread via clang ext_vector float2 (8 B/lane -> 512
// B/wave transactions; native vector type so __builtin_nontemporal_store
// accepts it). Register sliding window (HALO=30 + TT=8), nontemporal stores
// so the 537 MB write stream doesn't evict x from L2/L3. Each block: 512
// channels x 128-timestep strip.

#define BB 4
#define LL 4096
#define CC 2048
#define TT 8       // timesteps per inner iteration
#define HALO 30    // max kernel size - 1
#define STRIP 128  // timesteps per block

typedef float v2f __attribute__((ext_vector_type(2)));

__global__ __launch_bounds__(256) void fir_fused_f2(
    const float* __restrict__ x,
    const float* __restrict__ w0, const float* __restrict__ w1,
    const float* __restrict__ w2, const float* __restrict__ w3,
    float* __restrict__ out)
{
    const int c0 = blockIdx.x * 512 + threadIdx.x * 2;  // 2 adjacent channels
    const int tb = blockIdx.y * STRIP;
    const int b  = blockIdx.z;

    const long long base = (long long)b * LL * CC + c0;

    // --- weights for both channels into registers
    v2f a0[3], a1[7], a2[15], a3[31];
#pragma unroll
    for (int j = 0; j < 3;  ++j) { a0[j].x = w0[c0 * 3  + j]; a0[j].y = w0[(c0 + 1) * 3  + j]; }
#pragma unroll
    for (int j = 0; j < 7;  ++j) { a1[j].x = w1[c0 * 7  + j]; a1[j].y = w1[(c0 + 1) * 7  + j]; }
#pragma unroll
    for (int j = 0; j < 15; ++j) { a2[j].x = w2[c0 * 15 + j]; a2[j].y = w2[(c0 + 1) * 15 + j]; }
#pragma unroll
    for (int j = 0; j < 31; ++j) { a3[j].x = w3[c0 * 31 + j]; a3[j].y = w3[(c0 + 1) * 31 + j]; }

    // --- prologue: halo window [tb-30, tb)
    v2f xs[HALO + TT];
#pragma unroll
    for (int j = 0; j < HALO; ++j) {
        const int t = tb - HALO + j;
        xs[j] = (t >= 0) ? *reinterpret_cast<const v2f*>(x + base + (long long)t * CC)
                         : (v2f)(0.0f);
    }

    const long long N = (long long)BB * LL * CC;
    float* __restrict__ o0 = out;
    float* __restrict__ o1 = out + N;
    float* __restrict__ o2 = out + 2 * N;
    float* __restrict__ o3 = out + 3 * N;

    for (int it = 0; it < STRIP / TT; ++it) {
        const int t0 = tb + it * TT;

        // load TT new timesteps (coalesced 512 B/wave each)
#pragma unroll
        for (int j = 0; j < TT; ++j)
            xs[HALO + j] = *reinterpret_cast<const v2f*>(x + base + (long long)(t0 + j) * CC);

        // compute + stream out
#pragma unroll
        for (int t = 0; t < TT; ++t) {
            v2f y0 = (v2f)(0.f), y1 = (v2f)(0.f), y2 = (v2f)(0.f), y3 = (v2f)(0.f);
#pragma unroll
            for (int j = 0; j < 31; ++j) y3 += a3[j] * xs[t + j];
#pragma unroll
            for (int j = 0; j < 15; ++j) y2 += a2[j] * xs[t + 16 + j];
#pragma unroll
            for (int j = 0; j < 7;  ++j) y1 += a1[j] * xs[t + 24 + j];
#pragma unroll
            for (int j = 0; j < 3;  ++j) y0 += a0[j] * xs[t + 28 + j];

            const long long oidx = base + (long long)(t0 + t) * CC;
            __builtin_nontemporal_store(y0, reinterpret_cast<v2f*>(o0 + oidx));
            __builtin_nontemporal_store(y1, reinterpret_cast<v2f*>(o1 + oidx));
            __builtin_nontemporal_store(y2, reinterpret_cast<v2f*>(o2 + oidx));
            __builtin_nontemporal_store(y3, reinterpret_cast<v2f*>(o3 + oidx));
        }

        // slide window: carry last HALO values forward (register moves)
#pragma unroll
        for (int j = 0; j < HALO; ++j) xs[j] = xs[TT + j];
    }
}

extern "C" void kernel_launch(void* const* d_in, const int* in_sizes, int n_in,
                              void* d_out, int out_size, void* d_ws, size_t ws_size,
                              hipStream_t stream)
{
    const float* x  = (const float*)d_in[0];
    const float* w0 = (const float*)d_in[1];
    const float* w1 = (const float*)d_in[2];
    const float* w2 = (const float*)d_in[3];
    const float* w3 = (const float*)d_in[4];
    float* out = (float*)d_out;

    dim3 grid(CC / 512, LL / STRIP, BB);  // (4, 32, 4) = 512 blocks
    dim3 block(256);
    hipLaunchKernelGGL(fir_fused_f2, grid, block, 0, stream,
                       x, w0, w1, w2, w3, out);
}